// Round 8
// baseline (361.288 us; speedup 1.0000x reference)
//
#include <hip/hip_runtime.h>
#include <hip/hip_bf16.h>
#include <stdint.h>

typedef unsigned short u16;
typedef __attribute__((ext_vector_type(8))) short short8;
typedef __attribute__((ext_vector_type(4))) float floatx4;
typedef __attribute__((ext_vector_type(4))) unsigned short ushort4_t;

#define BT 200      // B*T
#define NOBJ 30
#define KP2 4224    // 4097 padded to 3 z-slices x 22 iters x 64
#define DIN 4097
#define DH1 512
#define DH2 256
#define DFF 512
#define MPAD 6016
#define CHZ 176     // k-chunks (of 8) per z-slice
#define NBIGW (132*16)   // fold_big blocks (4224/32 x 512/32)
#define NSMALL 512
#define NCONV (BT*2)     // full-density sum_convert blocks (c8 0..511)
#define NPAD 13          // pad-column writer (c8 512..527): 200*16 = 3200 thr
#define NZERO 16

#define PSTR1 ((size_t)6000 * DH1)   // hacc partial stride
#define PSTR2 ((size_t)6000 * DH2)   // hacc2 partial stride

__device__ __forceinline__ u16 f2bf(float f) {
    union { float f; uint32_t u; } c; c.f = f;
    uint32_t u = c.u;
    u += 0x7FFF + ((u >> 16) & 1);
    return (u16)(u >> 16);
}

// async global->LDS DMA, 16B/lane; LDS dest is wave-uniform base + lane*16
__device__ __forceinline__ void load16_lds(const u16* g, u16* l) {
    __builtin_amdgcn_global_load_lds(
        (const __attribute__((address_space(1))) void*)g,
        (__attribute__((address_space(3))) void*)l, 16, 0, 0);
}

// tiled offset: tiles of 128 rows x (3 z x 22 iters x 64 k), storage
// [tile147 = y*3+z][i][row][slot]*8 ; slot = kw ^ (row&7)  (pre-swizzled)
__device__ __forceinline__ size_t tile_off(int ytile, int row, int c8) {
    int z = c8 / CHZ, rem = c8 - z * CHZ;
    int i = rem >> 3, kw = rem & 7;
    int ks = kw ^ (row & 7);
    return ((((size_t)(ytile * 3 + z) * 22 + i) * 128 + row) * 64) + ks * 8;
}

// ======== prep_all: conv (full-density) | pad | zero | fold_small | fold_big ==
__global__ __launch_bounds__(256, 4)
void prep_all(const float* __restrict__ W1a, const float* __restrict__ W2a,
              const float* __restrict__ W1b, const float* __restrict__ W2b,
              const float* __restrict__ feat, const float* __restrict__ depth,
              u16* __restrict__ Wc1T, u16* __restrict__ W2aTs,
              u16* __restrict__ Wc2T, u16* __restrict__ W2bTs,
              u16* __restrict__ XbT, u16* __restrict__ SbT,
              float* __restrict__ zeroBase, size_t zeroQuads) {
    __shared__ float t1[32][33];
    __shared__ float t2[32][33];
    int bid = blockIdx.x, tid = threadIdx.x;
    if (bid < NCONV) {
        // -------- sum_convert: c8 0..511 (k<4096 always), 10-way groups ----
        int bt = bid >> 1;
        int c8 = ((bid & 1) << 8) + tid;          // 0..511, all threads active
        int k8 = c8 * 8;
        int zc = c8 / CHZ, rem = c8 - zc * CHZ;
        int ic = rem >> 3, kwc = rem & 7;
        const float* fb = feat + (size_t)bt * NOBJ * 4096 + k8;
        float s[8] = {};
        #pragma unroll 1
        for (int n0 = 0; n0 < NOBJ; n0 += 10) {
            float4 va[10], vb[10];
            #pragma unroll
            for (int u = 0; u < 10; u++) {
                const float* p = fb + (size_t)(n0 + u) * 4096;
                va[u] = *(const float4*)p;
                vb[u] = *(const float4*)(p + 4);
            }
            #pragma unroll
            for (int u = 0; u < 10; u++) {
                int r = bt * NOBJ + n0 + u;
                float v[8] = {va[u].x, va[u].y, va[u].z, va[u].w,
                              vb[u].x, vb[u].y, vb[u].z, vb[u].w};
                short8 o;
                #pragma unroll
                for (int e = 0; e < 8; e++) { s[e] += v[e]; o[e] = (short)f2bf(v[e]); }
                size_t off = ((((size_t)((r >> 7) * 3 + zc) * 22 + ic) * 128
                               + (r & 127)) * 64) + (size_t)(kwc ^ (r & 7)) * 8;
                *(short8*)(XbT + off) = o;
            }
        }
        short8 so;
        #pragma unroll
        for (int e = 0; e < 8; e++) so[e] = (short)f2bf(s[e]);
        {
            int r = bt;
            size_t off = ((((size_t)((r >> 7) * 3 + zc) * 22 + ic) * 128
                           + (r & 127)) * 64) + (size_t)(kwc ^ (r & 7)) * 8;
            *(short8*)(SbT + off) = so;
        }
    } else if (bid < NCONV + NPAD) {
        // -------- pad columns c8 512..527: zeros + depth at k=4096 --------
        int idx = (bid - NCONV) * 256 + tid;      // 0..3327
        if (idx < 3200) {
            int bt = idx >> 4;
            int c8 = 512 + (idx & 15);
            int rem = c8 - 2 * CHZ;               // 160..175 (zc = 2)
            int ic = rem >> 3, kwc = rem & 7;
            bool isd = (c8 == 512);
            float dsum = 0.f;
            for (int n = 0; n < NOBJ; n++) {
                int r = bt * NOBJ + n;
                short8 o = {};
                if (isd) { float d = depth[r]; dsum += d; o[0] = (short)f2bf(d); }
                size_t off = ((((size_t)((r >> 7) * 3 + 2) * 22 + ic) * 128
                               + (r & 127)) * 64) + (size_t)(kwc ^ (r & 7)) * 8;
                *(short8*)(XbT + off) = o;
            }
            short8 so = {};
            if (isd) so[0] = (short)f2bf(dsum);
            int r = bt;
            size_t off = ((((size_t)((r >> 7) * 3 + 2) * 22 + ic) * 128
                           + (r & 127)) * 64) + (size_t)(kwc ^ (r & 7)) * 8;
            *(short8*)(SbT + off) = so;
        }
    } else if (bid < NCONV + NPAD + NZERO) {
        int zid = bid - NCONV - NPAD;
        float4* p = (float4*)zeroBase;
        float4 zz = {0.f, 0.f, 0.f, 0.f};
        for (size_t idx = (size_t)zid * 256 + tid; idx < zeroQuads; idx += (size_t)NZERO * 256)
            p[idx] = zz;
    } else if (bid < NCONV + NPAD + NZERO + NSMALL) {
        int idx = (bid - NCONV - NPAD - NZERO) * 256 + tid;   // 256*512 total
        int j = idx >> 9, k = idx & 511;
        float a = W1b[k * DH2 + j];
        float b = W2b[k * DH2 + j] * (1.f / 29.f);
        Wc2T[j * DH1 + k]  = f2bf(a - b);
        W2bTs[j * DH1 + k] = f2bf(b);
    } else {
        int b2 = bid - NCONV - NPAD - NZERO - NSMALL;
        int kb = (b2 % 132) * 32, jb = (b2 / 132) * 32;
        int tx = tid & 31, ty = tid >> 5;   // 32 x 8
        #pragma unroll
        for (int r = 0; r < 32; r += 8) {
            int k = kb + ty + r, j = jb + tx;
            float a = 0.f, b = 0.f;
            if (k < DIN) { a = W1a[k * DH1 + j]; b = W2a[k * DH1 + j]; }
            float bs = b * (1.f / 29.f);
            t1[ty + r][tx] = a - bs;
            t2[ty + r][tx] = bs;
        }
        __syncthreads();
        #pragma unroll
        for (int r = 0; r < 32; r += 8) {
            int j = jb + ty + r, k = kb + tx;
            int x = j >> 7, row = j & 127;
            size_t off = tile_off(x, row, k >> 3) + (k & 7);
            Wc1T[off]  = f2bf(t1[tx][ty + r]);
            W2aTs[off] = f2bf(t2[tx][ty + r]);
        }
    }
}

// ======== gemmA: 128x128 bf16 MFMA, plain-store split-K, XCD swizzle ========
__global__ __launch_bounds__(256) void gemmA(
    const u16* __restrict__ XbT, const u16* __restrict__ WaT,
    const u16* __restrict__ SbT, const u16* __restrict__ WsT,
    float* __restrict__ haccP, float* __restrict__ uOut) {
    __shared__ __align__(16) u16 Al[8192];   // 16 KB
    __shared__ __align__(16) u16 Bl[8192];   // 16 KB
    int bid = blockIdx.x;
    const u16 *Abase, *Bbase;
    float* outF;
    int m0, n0, M;
    bool useAtomic;
    if (bid < 564) {
        // XCD-bijective swizzle (564 = 8*70+4). Measured: FETCH 112->41 MB.
        int xcd = bid & 7, slot = bid >> 3;
        int lid = (xcd < 4 ? xcd * 71 : 284 + (xcd - 4) * 70) + slot;
        int x = lid & 3, y = (lid >> 2) % 47, z = lid / 188;
        Abase = XbT + (size_t)((y * 3 + z) * 22) * 8192;
        Bbase = WaT + (size_t)((x * 3 + z) * 22) * 8192;
        outF = haccP + (size_t)z * PSTR1;   // exclusive partial -> plain store
        M = 6000; m0 = y * 128; n0 = x * 128; useAtomic = false;
    } else {
        int rem = bid - 564;
        int x = rem & 3, y = (rem >> 2) & 1, z = rem >> 3;
        Abase = SbT + (size_t)((y * 3 + z) * 22) * 8192;
        Bbase = WsT + (size_t)((x * 3 + z) * 22) * 8192;
        outF = uOut; M = BT; m0 = y * 128; n0 = x * 128; useAtomic = true;
    }
    int tid = threadIdx.x, lane = tid & 63, w = tid >> 6;
    floatx4 acc[4][4] = {};
    int lrow = lane & 15, q = lane >> 4;
    int wm = (w & 1) * 64, wn = (w >> 1) * 64;
    int swz = lrow & 7;

    for (int i = 0; i < 22; i++) {
        const u16* as = Abase + (size_t)i * 8192;
        const u16* bs = Bbase + (size_t)i * 8192;
        #pragma unroll
        for (int it = 0; it < 4; it++) {
            load16_lds(as + (it * 256 + tid) * 8, Al + it * 2048 + w * 512);
            load16_lds(bs + (it * 256 + tid) * 8, Bl + it * 2048 + w * 512);
        }
        __syncthreads();
        #pragma unroll
        for (int h = 0; h < 2; h++) {
            int ci = h * 4 + q;
            int so = (ci ^ swz) * 8;
            short8 af[4], bfv[4];
            #pragma unroll
            for (int ii = 0; ii < 4; ii++)
                af[ii] = *(short8*)(Al + (wm + ii * 16 + lrow) * 64 + so);
            #pragma unroll
            for (int j = 0; j < 4; j++)
                bfv[j] = *(short8*)(Bl + (wn + j * 16 + lrow) * 64 + so);
            #pragma unroll
            for (int ii = 0; ii < 4; ii++)
                #pragma unroll
                for (int j = 0; j < 4; j++)
                    acc[ii][j] = __builtin_amdgcn_mfma_f32_16x16x32_bf16(af[ii], bfv[j], acc[ii][j], 0, 0, 0);
        }
        __syncthreads();
    }

    if (useAtomic) {
        #pragma unroll
        for (int ii = 0; ii < 4; ii++)
            #pragma unroll
            for (int j = 0; j < 4; j++)
                #pragma unroll
                for (int r = 0; r < 4; r++) {
                    int row = m0 + wm + ii * 16 + q * 4 + r;
                    int col = n0 + wn + j * 16 + lrow;
                    if (row < M)
                        atomicAdd(&outF[(size_t)row * DH1 + col], acc[ii][j][r]);
                }
    } else {
        #pragma unroll
        for (int ii = 0; ii < 4; ii++)
            #pragma unroll
            for (int j = 0; j < 4; j++)
                #pragma unroll
                for (int r = 0; r < 4; r++) {
                    int row = m0 + wm + ii * 16 + q * 4 + r;
                    int col = n0 + wn + j * 16 + lrow;
                    if (row < M)
                        outF[(size_t)row * DH1 + col] = acc[ii][j][r];
                }
    }
}

// ======== gemmB: 64x128 bf16 MFMA, BK=64, plain-store split-K, XCD swizzle ==
__global__ __launch_bounds__(256) void gemmB(
    const u16* __restrict__ hb, const u16* __restrict__ Wc2T,
    const u16* __restrict__ Shb, const u16* __restrict__ W2bTs,
    float* __restrict__ hacc2P, float* __restrict__ u2Out) {
    __shared__ __align__(16) u16 Al[64 * 64];    // 8 KB
    __shared__ __align__(16) u16 Bl[128 * 64];   // 16 KB
    int bid = blockIdx.x;
    const u16 *A, *B;
    float* outF;
    int m0, n0, kbeg, M;
    bool useAtomic;
    if (bid < 376) {
        // XCD-bijective swizzle (376 = 8*47 exactly)
        int xcd = bid & 7, slot = bid >> 3;
        int lid = xcd * 47 + slot;
        int x = lid & 1, y = (lid >> 1) % 94, z = lid / 188;
        A = hb; B = Wc2T; M = 6000;
        outF = hacc2P + (size_t)z * PSTR2;
        m0 = y * 64; n0 = x * 128; kbeg = z * 256; useAtomic = false;
    } else {
        int rem = bid - 376;
        int x = rem & 1, y = (rem >> 1) & 3, z = rem >> 3;
        A = Shb; B = W2bTs; outF = u2Out; M = BT;
        m0 = y * 64; n0 = x * 128; kbeg = z * 256; useAtomic = true;
    }
    int kend = kbeg + 256;
    const int N = DH2, K = DH1;
    int tid = threadIdx.x;
    int lane = tid & 63, w = tid >> 6;
    int srow = tid >> 3, kslot = tid & 7;
    floatx4 acc[2][4] = {};
    int lrow = lane & 15, q = lane >> 4;
    int wm = (w & 1) * 32, wn = (w >> 1) * 64;
    int swz = lrow & 7;

    for (int kb = kbeg; kb < kend; kb += 64) {
        #pragma unroll
        for (int it = 0; it < 2; it++) {
            int row = it * 32 + srow;
            int kph = kslot ^ (row & 7);
            load16_lds(A + (size_t)(m0 + row) * K + kb + kph * 8,
                       Al + it * 2048 + w * 512);
        }
        #pragma unroll
        for (int it = 0; it < 4; it++) {
            int row = it * 32 + srow;
            int kph = kslot ^ (row & 7);
            load16_lds(B + (size_t)(n0 + row) * K + kb + kph * 8,
                       Bl + it * 2048 + w * 512);
        }
        __syncthreads();
        #pragma unroll
        for (int h = 0; h < 2; h++) {
            int ci = h * 4 + q;
            int so = (ci ^ swz) * 8;
            short8 af[2], bfv[4];
            #pragma unroll
            for (int i = 0; i < 2; i++)
                af[i] = *(short8*)(Al + (wm + i * 16 + lrow) * 64 + so);
            #pragma unroll
            for (int j = 0; j < 4; j++)
                bfv[j] = *(short8*)(Bl + (wn + j * 16 + lrow) * 64 + so);
            #pragma unroll
            for (int i = 0; i < 2; i++)
                #pragma unroll
                for (int j = 0; j < 4; j++)
                    acc[i][j] = __builtin_amdgcn_mfma_f32_16x16x32_bf16(af[i], bfv[j], acc[i][j], 0, 0, 0);
        }
        __syncthreads();
    }

    if (useAtomic) {
        #pragma unroll
        for (int i = 0; i < 2; i++)
            #pragma unroll
            for (int j = 0; j < 4; j++)
                #pragma unroll
                for (int r = 0; r < 4; r++) {
                    int row = m0 + wm + i * 16 + q * 4 + r;
                    int col = n0 + wn + j * 16 + lrow;
                    if (row < M)
                        atomicAdd(&outF[(size_t)row * N + col], acc[i][j][r]);
                }
    } else {
        #pragma unroll
        for (int i = 0; i < 2; i++)
            #pragma unroll
            for (int j = 0; j < 4; j++)
                #pragma unroll
                for (int r = 0; r < 4; r++) {
                    int row = m0 + wm + i * 16 + q * 4 + r;
                    int col = n0 + wn + j * 16 + lrow;
                    if (row < M)
                        outF[(size_t)row * N + col] = acc[i][j][r];
                }
    }
}

// -------- reduce1: h = relu(sum_z haccP + u + b1a) -> bf16 hb; node-sum -> Shb --
__global__ void reduce1(const float* __restrict__ haccP, const float* __restrict__ u,
                        const float* __restrict__ b1a,
                        u16* __restrict__ hb, u16* __restrict__ Shb) {
    __shared__ float sl[128];
    int bt = blockIdx.x, c0 = blockIdx.y * 128;
    int lc = threadIdx.x & 127, rp = threadIdx.x >> 7;
    int col = c0 + lc;
    float ub = u[bt * DH1 + col] + b1a[col];
    float s = 0.f;
    for (int n = rp; n < NOBJ; n += 2) {
        size_t idx = (size_t)(bt * NOBJ + n) * DH1 + col;
        float v = haccP[idx] + haccP[idx + PSTR1] + haccP[idx + 2 * PSTR1] + ub;
        v = v > 0.f ? v : 0.f;
        hb[idx] = f2bf(v);
        s += v;
    }
    if (rp == 0) sl[lc] = s;
    __syncthreads();
    if (rp == 1) Shb[bt * DH1 + col] = f2bf(sl[lc] + s);
}

// -------- reduce2_qkv: 1024 threads, 4-way k-split (16 waves hide L2 latency) --
__global__ __launch_bounds__(1024) void reduce2_qkv(
    const float* __restrict__ hacc2P, const float* __restrict__ u2,
    const float* __restrict__ b1b,
    const float* __restrict__ Wq, const float* __restrict__ Wk,
    const float* __restrict__ Wv,
    float* __restrict__ g, float* __restrict__ q,
    float* __restrict__ k, float* __restrict__ v) {
    __shared__ float gl[DH2];
    __shared__ float sA[4 * DH2];
    __shared__ float sQ[4 * DH2];
    __shared__ float sK[4 * DH2];
    __shared__ float sV[4 * DH2];
    int bt = blockIdx.x, tid = threadIdx.x;
    int j = tid & 255, part = tid >> 8;
    // phase 1: partial relu-sum over objects (n strided by part)
    {
        float ub = u2[bt * DH2 + j] + b1b[j];
        float s = 0.f;
        for (int n = part; n < NOBJ; n += 4) {
            size_t idx = (size_t)(bt * NOBJ + n) * DH2 + j;
            float vv = hacc2P[idx] + hacc2P[idx + PSTR2] + ub;
            s += vv > 0.f ? vv : 0.f;
        }
        sA[part * DH2 + j] = s;
    }
    __syncthreads();
    if (tid < DH2) {
        float a = (sA[tid] + sA[DH2 + tid] + sA[2 * DH2 + tid] + sA[3 * DH2 + tid]) * (1.f / 30.f);
        gl[tid] = a;
        g[bt * DH2 + tid] = a;
    }
    __syncthreads();
    // phase 2: q/k/v matmuls, k-split 4 ways (coalesced weight reads)
    {
        float aq = 0.f, ak = 0.f, av = 0.f;
        int k0 = part * 64;
        for (int kk = k0; kk < k0 + 64; kk++) {
            float x = gl[kk];
            aq += x * Wq[kk * DH2 + j];
            ak += x * Wk[kk * DH2 + j];
            av += x * Wv[kk * DH2 + j];
        }
        sQ[part * DH2 + j] = aq;
        sK[part * DH2 + j] = ak;
        sV[part * DH2 + j] = av;
    }
    __syncthreads();
    if (tid < DH2) {
        q[bt * DH2 + tid] = sQ[tid] + sQ[DH2 + tid] + sQ[2 * DH2 + tid] + sQ[3 * DH2 + tid];
        k[bt * DH2 + tid] = sK[tid] + sK[DH2 + tid] + sK[2 * DH2 + tid] + sK[3 * DH2 + tid];
        v[bt * DH2 + tid] = sV[tid] + sV[DH2 + tid] + sV[2 * DH2 + tid] + sV[3 * DH2 + tid];
    }
}

// -------- attn_head: 1024 threads, every matmul 4-way k-split --------
__device__ __forceinline__ float bsum1024(float val, volatile float* red) {
    #pragma unroll
    for (int o = 32; o > 0; o >>= 1) val += __shfl_down(val, o);
    int w = threadIdx.x >> 6;
    __syncthreads();
    if ((threadIdx.x & 63) == 0) red[w] = val;
    __syncthreads();
    // only waves 0-3 carry data (threads >=256 contribute zeros)
    return red[0] + red[1] + red[2] + red[3];
}

__global__ __launch_bounds__(1024) void attn_head(
    const float* __restrict__ qg, const float* __restrict__ kg,
    const float* __restrict__ vg, const float* __restrict__ g,
    const float* __restrict__ Wo,
    const float* __restrict__ ln1g, const float* __restrict__ ln1b,
    const float* __restrict__ Wf1, const float* __restrict__ bf1,
    const float* __restrict__ Wf2, const float* __restrict__ bf2,
    const float* __restrict__ ln2g, const float* __restrict__ ln2b,
    const float* __restrict__ Wc, const float* __restrict__ bc,
    float* __restrict__ outP) {
    __shared__ float ql[DH2];
    __shared__ float scl[4][128];
    __shared__ float ctxl[DH2];
    __shared__ float yl[DH2];
    __shared__ float ffl[DFF];
    __shared__ float red[16];
    __shared__ float scratch[1024];
    int row = blockIdx.x, tid = threadIdx.x;
    int base = (row >= 100) ? 100 : 0;
    if (tid < DH2) ql[tid] = qg[row * DH2 + tid];
    __syncthreads();

    // scores: 512 workers, one (head, s) each
    if (tid < 512) {
        int h = tid >> 7, s = tid & 127;
        if (s < 100) {
            const float* kr = kg + (size_t)(base + s) * DH2 + h * 64;
            float a = 0.f;
            #pragma unroll 8
            for (int d = 0; d < 64; d++) a += ql[h * 64 + d] * kr[d];
            scl[h][s] = a * 0.125f;
        }
    }
    __syncthreads();

    // softmax: waves 0-3, one head per wave
    if (tid < 256) {
        int w = tid >> 6, lane = tid & 63;
        int s2 = 64 + lane;
        float a  = scl[w][lane];
        float b2 = (s2 < 100) ? scl[w][s2] : -1e30f;
        float m = fmaxf(a, b2);
        #pragma unroll
        for (int o = 32; o > 0; o >>= 1) m = fmaxf(m, __shfl_down(m, o));
        m = __shfl(m, 0);
        float e1 = __expf(a - m);
        float e2 = (s2 < 100) ? __expf(b2 - m) : 0.f;
        float sm = e1 + e2;
        #pragma unroll
        for (int o = 32; o > 0; o >>= 1) sm += __shfl_down(sm, o);
        sm = __shfl(sm, 0);
        float r = 1.f / sm;
        scl[w][lane] = e1 * r;
        if (s2 < 100) scl[w][s2] = e2 * r;
    }
    __syncthreads();

    // PV: 4-way s-split (25 each)
    {
        int oc = tid & 255, part = tid >> 8;
        int h = oc >> 6;
        float o = 0.f;
        for (int s = part * 25; s < part * 25 + 25; s++)
            o += scl[h][s] * vg[(size_t)(base + s) * DH2 + oc];
        scratch[part * 256 + oc] = o;
    }
    __syncthreads();
    if (tid < 256)
        ctxl[tid] = scratch[tid] + scratch[256 + tid] + scratch[512 + tid] + scratch[768 + tid];
    __syncthreads();

    // Wo: 4-way k-split (64 each), coalesced weight reads
    {
        int oc = tid & 255, part = tid >> 8;
        float o = 0.f;
        for (int kk = part * 64; kk < part * 64 + 64; kk++)
            o += ctxl[kk] * Wo[kk * DH2 + oc];
        scratch[part * 256 + oc] = o;
    }
    __syncthreads();
    float t = 0.f, y = 0.f;
    if (tid < 256) {
        float o = scratch[tid] + scratch[256 + tid] + scratch[512 + tid] + scratch[768 + tid];
        t = g[row * DH2 + tid] + o;
    }
    float mu  = bsum1024(tid < 256 ? t : 0.f, red) * (1.f / DH2);
    float ex2 = bsum1024(tid < 256 ? t * t : 0.f, red) * (1.f / DH2);
    if (tid < 256) {
        y = (t - mu) * rsqrtf(ex2 - mu * mu + 1e-5f) * ln1g[tid] + ln1b[tid];
        yl[tid] = y;
    }
    __syncthreads();

    // FFN1: 512 outs, 2-way k-split (128 each)
    {
        int oc = tid & 511, part = tid >> 9;
        float a = 0.f;
        for (int kk = part * 128; kk < part * 128 + 128; kk++)
            a += yl[kk] * Wf1[kk * DFF + oc];
        scratch[part * 512 + oc] = a;
    }
    __syncthreads();
    if (tid < 512) {
        float a = scratch[tid] + scratch[512 + tid] + bf1[tid];
        ffl[tid] = a > 0.f ? a : 0.f;
    }
    __syncthreads();

    // FFN2: 256 outs, 4-way k-split (128 each)
    {
        int oc = tid & 255, part = tid >> 8;
        float o = 0.f;
        for (int kk = part * 128; kk < part * 128 + 128; kk++)
            o += ffl[kk] * Wf2[kk * DH2 + oc];
        scratch[part * 256 + oc] = o;
    }
    __syncthreads();
    float z0 = 0.f;
    if (tid < 256)
        z0 = y + bf2[tid] + scratch[tid] + scratch[256 + tid] + scratch[512 + tid] + scratch[768 + tid];
    float mu2  = bsum1024(tid < 256 ? z0 : 0.f, red) * (1.f / DH2);
    float ex22 = bsum1024(tid < 256 ? z0 * z0 : 0.f, red) * (1.f / DH2);
    float zv = 0.f;
    if (tid < 256)
        zv = (z0 - mu2) * rsqrtf(ex22 - mu2 * mu2 + 1e-5f) * ln2g[tid] + ln2b[tid];
    float logit = bsum1024(tid < 256 ? zv * Wc[tid] : 0.f, red) + bc[0];
    if (tid == 0) {
        outP[row]      = 1.f / (1.f + __expf(-logit));
        outP[BT + row] = 0.f;
    }
}

// ---------------- launch ----------------
extern "C" void kernel_launch(void* const* d_in, const int* in_sizes, int n_in,
                              void* d_out, int out_size, void* d_ws, size_t ws_size,
                              hipStream_t stream) {
    const float* feat  = (const float*)d_in[0];
    const float* depth = (const float*)d_in[1];
    const float* W1a = (const float*)d_in[2];
    const float* W2a = (const float*)d_in[3];
    const float* b1a = (const float*)d_in[4];
    const float* W1b = (const float*)d_in[5];
    const float* W2b = (const float*)d_in[6];
    const float* b1b = (const float*)d_in[7];
    const float* Wq  = (const float*)d_in[8];
    const float* Wk  = (const float*)d_in[9];
    const float* Wv  = (const float*)d_in[10];
    const float* Wo  = (const float*)d_in[11];
    const float* ln1g = (const float*)d_in[12];
    const float* ln1b = (const float*)d_in[13];
    const float* Wf1 = (const float*)d_in[14];
    const float* bf1 = (const float*)d_in[15];
    const float* Wf2 = (const float*)d_in[16];
    const float* bf2 = (const float*)d_in[17];
    const float* ln2g = (const float*)d_in[18];
    const float* ln2b = (const float*)d_in[19];
    const float* Wc  = (const float*)d_in[20];
    const float* bc  = (const float*)d_in[21];
    float* out = (float*)d_out;
    char* ws = (char*)d_ws;

    size_t off = 0;
    u16* XbT   = (u16*)(ws + off); off += (size_t)MPAD * KP2 * 2;    // 50.8 MB
    u16* SbT   = (u16*)(ws + off); off += (size_t)256 * KP2 * 2;     //  2.2 MB
    u16* Wc1T  = (u16*)(ws + off); off += (size_t)DH1 * KP2 * 2;     //  4.3 MB
    u16* W2aTs = (u16*)(ws + off); off += (size_t)DH1 * KP2 * 2;
    u16* Wc2T  = (u16*)(ws + off); off += (size_t)DH2 * DH1 * 2;
    u16* W2bTs = (u16*)(ws + off); off += (size_t)DH2 * DH1 * 2;
    u16* Shb   = (u16*)(ws + off); off += (size_t)256 * DH1 * 2;
    // small zero region (u/u2 only; hacc/hacc2 partials are store-once)
    char* zBase = ws + off;
    float* u     = (float*)(ws + off); off += (size_t)BT * DH1 * 4;
    float* u2    = (float*)(ws + off); off += (size_t)BT * DH2 * 4;
    size_t zeroQuads = (size_t)(ws + off - zBase) / 16;
    // split-K partial buffers: gemmA writes 3 x 12.3 MB plain-store partials;
    // after reduce1 consumes them, gemmB reuses the SAME region for its
    // 2 x 6.1 MB partials (haccP dead by then).
    float* haccP  = (float*)(ws + off); off += 3 * PSTR1 * 4;        // 36.9 MB
    float* hacc2P = haccP;
    // aliases: hb reuses XbT (dead after gemmA); g/q/k/v reuse SbT
    u16* hb = XbT;
    float* g = (float*)SbT;
    float* q = g + BT * DH2;
    float* k = q + BT * DH2;
    float* v = k + BT * DH2;

    prep_all<<<NCONV + NPAD + NZERO + NSMALL + NBIGW, 256, 0, stream>>>(
        W1a, W2a, W1b, W2b, feat, depth,
        Wc1T, W2aTs, Wc2T, W2bTs, XbT, SbT, (float*)zBase, zeroQuads);
    // haccP[z] = XbT@Wc1T (564 blocks, z=3, plain store) ; u += SbT@W2aTs (24)
    gemmA<<<564 + 24, 256, 0, stream>>>(XbT, Wc1T, SbT, W2aTs, haccP, u);
    reduce1<<<dim3(BT, 4), 256, 0, stream>>>(haccP, u, b1a, hb, Shb);
    // hacc2P[z] = hb@Wc2T (376 blocks, z=2, plain store) ; u2 += Shb@W2bTs (16)
    gemmB<<<376 + 16, 256, 0, stream>>>(hb, Wc2T, Shb, W2bTs, hacc2P, u2);
    reduce2_qkv<<<BT, 1024, 0, stream>>>(hacc2P, u2, b1b, Wq, Wk, Wv, g, q, k, v);
    attn_head<<<BT, 1024, 0, stream>>>(q, k, v, g, Wo, ln1g, ln1b, Wf1, bf1,
                                       Wf2, bf2, ln2g, ln2b, Wc, bc, out);
}

// Round 9
// 345.373 us; speedup vs baseline: 1.0461x; 1.0461x over previous
//
#include <hip/hip_runtime.h>
#include <hip/hip_bf16.h>
#include <stdint.h>

typedef unsigned short u16;
typedef __attribute__((ext_vector_type(8))) short short8;
typedef __attribute__((ext_vector_type(4))) float floatx4;
typedef __attribute__((ext_vector_type(4))) unsigned short ushort4_t;

#define BT 200      // B*T
#define NOBJ 30
#define KP2 4224    // 4097 padded to 3 z-slices x 22 iters x 64
#define DIN 4097
#define DH1 512
#define DH2 256
#define DFF 512
#define MPAD 6016
#define CHZ 176     // k-chunks (of 8) per z-slice
#define NBIGW (132*16)   // fold_big blocks (4224/32 x 512/32)
#define NSMALL 512
#define NCONV (BT*2)     // full-density sum_convert blocks (c8 0..511)
#define NPAD 13          // pad-column writer (c8 512..527): 200*16 = 3200 thr
#define NZERO 16

#define PSTR1 ((size_t)6000 * DH1)   // hacc partial stride
#define PSTR2 ((size_t)6000 * DH2)   // hacc2 partial stride

__device__ __forceinline__ u16 f2bf(float f) {
    union { float f; uint32_t u; } c; c.f = f;
    uint32_t u = c.u;
    u += 0x7FFF + ((u >> 16) & 1);
    return (u16)(u >> 16);
}

// async global->LDS DMA, 16B/lane; LDS dest is wave-uniform base + lane*16
__device__ __forceinline__ void load16_lds(const u16* g, u16* l) {
    __builtin_amdgcn_global_load_lds(
        (const __attribute__((address_space(1))) void*)g,
        (__attribute__((address_space(3))) void*)l, 16, 0, 0);
}

// stage a 64KB (16384-float) chunk into LDS, linear layout, 256 threads
__device__ __forceinline__ void stage64k(const float* src, float* dst, int tid) {
    int w = tid >> 6;
    #pragma unroll
    for (int it = 0; it < 16; it++)
        load16_lds((const u16*)src + (it * 256 + tid) * 8,
                   (u16*)dst + it * 2048 + w * 512);
}

// tiled offset: tiles of 128 rows x (3 z x 22 iters x 64 k), storage
// [tile147 = y*3+z][i][row][slot]*8 ; slot = kw ^ (row&7)  (pre-swizzled)
__device__ __forceinline__ size_t tile_off(int ytile, int row, int c8) {
    int z = c8 / CHZ, rem = c8 - z * CHZ;
    int i = rem >> 3, kw = rem & 7;
    int ks = kw ^ (row & 7);
    return ((((size_t)(ytile * 3 + z) * 22 + i) * 128 + row) * 64) + ks * 8;
}

// ======== prep_all: conv (full-density) | pad | zero | fold_small | fold_big ==
__global__ __launch_bounds__(256, 4)
void prep_all(const float* __restrict__ W1a, const float* __restrict__ W2a,
              const float* __restrict__ W1b, const float* __restrict__ W2b,
              const float* __restrict__ feat, const float* __restrict__ depth,
              u16* __restrict__ Wc1T, u16* __restrict__ W2aTs,
              u16* __restrict__ Wc2T, u16* __restrict__ W2bTs,
              u16* __restrict__ XbT, u16* __restrict__ SbT,
              float* __restrict__ zeroBase, size_t zeroQuads) {
    __shared__ float t1[32][33];
    __shared__ float t2[32][33];
    int bid = blockIdx.x, tid = threadIdx.x;
    if (bid < NCONV) {
        // -------- sum_convert: c8 0..511 (k<4096 always), 10-way groups ----
        int bt = bid >> 1;
        int c8 = ((bid & 1) << 8) + tid;          // 0..511, all threads active
        int k8 = c8 * 8;
        int zc = c8 / CHZ, rem = c8 - zc * CHZ;
        int ic = rem >> 3, kwc = rem & 7;
        const float* fb = feat + (size_t)bt * NOBJ * 4096 + k8;
        float s[8] = {};
        #pragma unroll 1
        for (int n0 = 0; n0 < NOBJ; n0 += 10) {
            float4 va[10], vb[10];
            #pragma unroll
            for (int u = 0; u < 10; u++) {
                const float* p = fb + (size_t)(n0 + u) * 4096;
                va[u] = *(const float4*)p;
                vb[u] = *(const float4*)(p + 4);
            }
            #pragma unroll
            for (int u = 0; u < 10; u++) {
                int r = bt * NOBJ + n0 + u;
                float v[8] = {va[u].x, va[u].y, va[u].z, va[u].w,
                              vb[u].x, vb[u].y, vb[u].z, vb[u].w};
                short8 o;
                #pragma unroll
                for (int e = 0; e < 8; e++) { s[e] += v[e]; o[e] = (short)f2bf(v[e]); }
                size_t off = ((((size_t)((r >> 7) * 3 + zc) * 22 + ic) * 128
                               + (r & 127)) * 64) + (size_t)(kwc ^ (r & 7)) * 8;
                *(short8*)(XbT + off) = o;
            }
        }
        short8 so;
        #pragma unroll
        for (int e = 0; e < 8; e++) so[e] = (short)f2bf(s[e]);
        {
            int r = bt;
            size_t off = ((((size_t)((r >> 7) * 3 + zc) * 22 + ic) * 128
                           + (r & 127)) * 64) + (size_t)(kwc ^ (r & 7)) * 8;
            *(short8*)(SbT + off) = so;
        }
    } else if (bid < NCONV + NPAD) {
        // -------- pad columns c8 512..527: zeros + depth at k=4096 --------
        int idx = (bid - NCONV) * 256 + tid;      // 0..3327
        if (idx < 3200) {
            int bt = idx >> 4;
            int c8 = 512 + (idx & 15);
            int rem = c8 - 2 * CHZ;               // 160..175 (zc = 2)
            int ic = rem >> 3, kwc = rem & 7;
            bool isd = (c8 == 512);
            float dsum = 0.f;
            for (int n = 0; n < NOBJ; n++) {
                int r = bt * NOBJ + n;
                short8 o = {};
                if (isd) { float d = depth[r]; dsum += d; o[0] = (short)f2bf(d); }
                size_t off = ((((size_t)((r >> 7) * 3 + 2) * 22 + ic) * 128
                               + (r & 127)) * 64) + (size_t)(kwc ^ (r & 7)) * 8;
                *(short8*)(XbT + off) = o;
            }
            short8 so = {};
            if (isd) so[0] = (short)f2bf(dsum);
            int r = bt;
            size_t off = ((((size_t)((r >> 7) * 3 + 2) * 22 + ic) * 128
                           + (r & 127)) * 64) + (size_t)(kwc ^ (r & 7)) * 8;
            *(short8*)(SbT + off) = so;
        }
    } else if (bid < NCONV + NPAD + NZERO) {
        int zid = bid - NCONV - NPAD;
        float4* p = (float4*)zeroBase;
        float4 zz = {0.f, 0.f, 0.f, 0.f};
        for (size_t idx = (size_t)zid * 256 + tid; idx < zeroQuads; idx += (size_t)NZERO * 256)
            p[idx] = zz;
    } else if (bid < NCONV + NPAD + NZERO + NSMALL) {
        int idx = (bid - NCONV - NPAD - NZERO) * 256 + tid;   // 256*512 total
        int j = idx >> 9, k = idx & 511;
        float a = W1b[k * DH2 + j];
        float b = W2b[k * DH2 + j] * (1.f / 29.f);
        Wc2T[j * DH1 + k]  = f2bf(a - b);
        W2bTs[j * DH1 + k] = f2bf(b);
    } else {
        int b2 = bid - NCONV - NPAD - NZERO - NSMALL;
        int kb = (b2 % 132) * 32, jb = (b2 / 132) * 32;
        int tx = tid & 31, ty = tid >> 5;   // 32 x 8
        #pragma unroll
        for (int r = 0; r < 32; r += 8) {
            int k = kb + ty + r, j = jb + tx;
            float a = 0.f, b = 0.f;
            if (k < DIN) { a = W1a[k * DH1 + j]; b = W2a[k * DH1 + j]; }
            float bs = b * (1.f / 29.f);
            t1[ty + r][tx] = a - bs;
            t2[ty + r][tx] = bs;
        }
        __syncthreads();
        #pragma unroll
        for (int r = 0; r < 32; r += 8) {
            int j = jb + ty + r, k = kb + tx;
            int x = j >> 7, row = j & 127;
            size_t off = tile_off(x, row, k >> 3) + (k & 7);
            Wc1T[off]  = f2bf(t1[tx][ty + r]);
            W2aTs[off] = f2bf(t2[tx][ty + r]);
        }
    }
}

// ======== gemmA: 128x128 bf16 MFMA, plain-store split-K, XCD swizzle ========
__global__ __launch_bounds__(256) void gemmA(
    const u16* __restrict__ XbT, const u16* __restrict__ WaT,
    const u16* __restrict__ SbT, const u16* __restrict__ WsT,
    float* __restrict__ haccP, float* __restrict__ uOut) {
    __shared__ __align__(16) u16 Al[8192];   // 16 KB
    __shared__ __align__(16) u16 Bl[8192];   // 16 KB
    int bid = blockIdx.x;
    const u16 *Abase, *Bbase;
    float* outF;
    int m0, n0, M;
    bool useAtomic;
    if (bid < 564) {
        // XCD-bijective swizzle (564 = 8*70+4). Measured: FETCH 112->41 MB.
        int xcd = bid & 7, slot = bid >> 3;
        int lid = (xcd < 4 ? xcd * 71 : 284 + (xcd - 4) * 70) + slot;
        int x = lid & 3, y = (lid >> 2) % 47, z = lid / 188;
        Abase = XbT + (size_t)((y * 3 + z) * 22) * 8192;
        Bbase = WaT + (size_t)((x * 3 + z) * 22) * 8192;
        outF = haccP + (size_t)z * PSTR1;   // exclusive partial -> plain store
        M = 6000; m0 = y * 128; n0 = x * 128; useAtomic = false;
    } else {
        int rem = bid - 564;
        int x = rem & 3, y = (rem >> 2) & 1, z = rem >> 3;
        Abase = SbT + (size_t)((y * 3 + z) * 22) * 8192;
        Bbase = WsT + (size_t)((x * 3 + z) * 22) * 8192;
        outF = uOut; M = BT; m0 = y * 128; n0 = x * 128; useAtomic = true;
    }
    int tid = threadIdx.x, lane = tid & 63, w = tid >> 6;
    floatx4 acc[4][4] = {};
    int lrow = lane & 15, q = lane >> 4;
    int wm = (w & 1) * 64, wn = (w >> 1) * 64;
    int swz = lrow & 7;

    for (int i = 0; i < 22; i++) {
        const u16* as = Abase + (size_t)i * 8192;
        const u16* bs = Bbase + (size_t)i * 8192;
        #pragma unroll
        for (int it = 0; it < 4; it++) {
            load16_lds(as + (it * 256 + tid) * 8, Al + it * 2048 + w * 512);
            load16_lds(bs + (it * 256 + tid) * 8, Bl + it * 2048 + w * 512);
        }
        __syncthreads();
        #pragma unroll
        for (int h = 0; h < 2; h++) {
            int ci = h * 4 + q;
            int so = (ci ^ swz) * 8;
            short8 af[4], bfv[4];
            #pragma unroll
            for (int ii = 0; ii < 4; ii++)
                af[ii] = *(short8*)(Al + (wm + ii * 16 + lrow) * 64 + so);
            #pragma unroll
            for (int j = 0; j < 4; j++)
                bfv[j] = *(short8*)(Bl + (wn + j * 16 + lrow) * 64 + so);
            #pragma unroll
            for (int ii = 0; ii < 4; ii++)
                #pragma unroll
                for (int j = 0; j < 4; j++)
                    acc[ii][j] = __builtin_amdgcn_mfma_f32_16x16x32_bf16(af[ii], bfv[j], acc[ii][j], 0, 0, 0);
        }
        __syncthreads();
    }

    if (useAtomic) {
        #pragma unroll
        for (int ii = 0; ii < 4; ii++)
            #pragma unroll
            for (int j = 0; j < 4; j++)
                #pragma unroll
                for (int r = 0; r < 4; r++) {
                    int row = m0 + wm + ii * 16 + q * 4 + r;
                    int col = n0 + wn + j * 16 + lrow;
                    if (row < M)
                        atomicAdd(&outF[(size_t)row * DH1 + col], acc[ii][j][r]);
                }
    } else {
        #pragma unroll
        for (int ii = 0; ii < 4; ii++)
            #pragma unroll
            for (int j = 0; j < 4; j++)
                #pragma unroll
                for (int r = 0; r < 4; r++) {
                    int row = m0 + wm + ii * 16 + q * 4 + r;
                    int col = n0 + wn + j * 16 + lrow;
                    if (row < M)
                        outF[(size_t)row * DH1 + col] = acc[ii][j][r];
                }
    }
}

// ======== gemmB: 64x128 bf16 MFMA, BK=64, plain-store split-K, XCD swizzle ==
__global__ __launch_bounds__(256) void gemmB(
    const u16* __restrict__ hb, const u16* __restrict__ Wc2T,
    const u16* __restrict__ Shb, const u16* __restrict__ W2bTs,
    float* __restrict__ hacc2P, float* __restrict__ u2Out) {
    __shared__ __align__(16) u16 Al[64 * 64];    // 8 KB
    __shared__ __align__(16) u16 Bl[128 * 64];   // 16 KB
    int bid = blockIdx.x;
    const u16 *A, *B;
    float* outF;
    int m0, n0, kbeg, M;
    bool useAtomic;
    if (bid < 376) {
        // XCD-bijective swizzle (376 = 8*47 exactly)
        int xcd = bid & 7, slot = bid >> 3;
        int lid = xcd * 47 + slot;
        int x = lid & 1, y = (lid >> 1) % 94, z = lid / 188;
        A = hb; B = Wc2T; M = 6000;
        outF = hacc2P + (size_t)z * PSTR2;
        m0 = y * 64; n0 = x * 128; kbeg = z * 256; useAtomic = false;
    } else {
        int rem = bid - 376;
        int x = rem & 1, y = (rem >> 1) & 3, z = rem >> 3;
        A = Shb; B = W2bTs; outF = u2Out; M = BT;
        m0 = y * 64; n0 = x * 128; kbeg = z * 256; useAtomic = true;
    }
    int kend = kbeg + 256;
    const int N = DH2, K = DH1;
    int tid = threadIdx.x;
    int lane = tid & 63, w = tid >> 6;
    int srow = tid >> 3, kslot = tid & 7;
    floatx4 acc[2][4] = {};
    int lrow = lane & 15, q = lane >> 4;
    int wm = (w & 1) * 32, wn = (w >> 1) * 64;
    int swz = lrow & 7;

    for (int kb = kbeg; kb < kend; kb += 64) {
        #pragma unroll
        for (int it = 0; it < 2; it++) {
            int row = it * 32 + srow;
            int kph = kslot ^ (row & 7);
            load16_lds(A + (size_t)(m0 + row) * K + kb + kph * 8,
                       Al + it * 2048 + w * 512);
        }
        #pragma unroll
        for (int it = 0; it < 4; it++) {
            int row = it * 32 + srow;
            int kph = kslot ^ (row & 7);
            load16_lds(B + (size_t)(n0 + row) * K + kb + kph * 8,
                       Bl + it * 2048 + w * 512);
        }
        __syncthreads();
        #pragma unroll
        for (int h = 0; h < 2; h++) {
            int ci = h * 4 + q;
            int so = (ci ^ swz) * 8;
            short8 af[2], bfv[4];
            #pragma unroll
            for (int i = 0; i < 2; i++)
                af[i] = *(short8*)(Al + (wm + i * 16 + lrow) * 64 + so);
            #pragma unroll
            for (int j = 0; j < 4; j++)
                bfv[j] = *(short8*)(Bl + (wn + j * 16 + lrow) * 64 + so);
            #pragma unroll
            for (int i = 0; i < 2; i++)
                #pragma unroll
                for (int j = 0; j < 4; j++)
                    acc[i][j] = __builtin_amdgcn_mfma_f32_16x16x32_bf16(af[i], bfv[j], acc[i][j], 0, 0, 0);
        }
        __syncthreads();
    }

    if (useAtomic) {
        #pragma unroll
        for (int i = 0; i < 2; i++)
            #pragma unroll
            for (int j = 0; j < 4; j++)
                #pragma unroll
                for (int r = 0; r < 4; r++) {
                    int row = m0 + wm + i * 16 + q * 4 + r;
                    int col = n0 + wn + j * 16 + lrow;
                    if (row < M)
                        atomicAdd(&outF[(size_t)row * N + col], acc[i][j][r]);
                }
    } else {
        #pragma unroll
        for (int i = 0; i < 2; i++)
            #pragma unroll
            for (int j = 0; j < 4; j++)
                #pragma unroll
                for (int r = 0; r < 4; r++) {
                    int row = m0 + wm + i * 16 + q * 4 + r;
                    int col = n0 + wn + j * 16 + lrow;
                    if (row < M)
                        outF[(size_t)row * N + col] = acc[i][j][r];
                }
    }
}

// -------- reduce1: h = relu(sum_z haccP + u + b1a) -> bf16 hb; node-sum -> Shb --
__global__ void reduce1(const float* __restrict__ haccP, const float* __restrict__ u,
                        const float* __restrict__ b1a,
                        u16* __restrict__ hb, u16* __restrict__ Shb) {
    __shared__ float sl[128];
    int bt = blockIdx.x, c0 = blockIdx.y * 128;
    int lc = threadIdx.x & 127, rp = threadIdx.x >> 7;
    int col = c0 + lc;
    float ub = u[bt * DH1 + col] + b1a[col];
    float s = 0.f;
    for (int n = rp; n < NOBJ; n += 2) {
        size_t idx = (size_t)(bt * NOBJ + n) * DH1 + col;
        float v = haccP[idx] + haccP[idx + PSTR1] + haccP[idx + 2 * PSTR1] + ub;
        v = v > 0.f ? v : 0.f;
        hb[idx] = f2bf(v);
        s += v;
    }
    if (rp == 0) sl[lc] = s;
    __syncthreads();
    if (rp == 1) Shb[bt * DH1 + col] = f2bf(sl[lc] + s);
}

// -------- reduce2_qkv: 256 thr, LDS-staged weight chunks (64KB each) --------
__global__ __launch_bounds__(256) void reduce2_qkv(
    const float* __restrict__ hacc2P, const float* __restrict__ u2,
    const float* __restrict__ b1b,
    const float* __restrict__ Wq, const float* __restrict__ Wk,
    const float* __restrict__ Wv,
    float* __restrict__ g, float* __restrict__ q,
    float* __restrict__ k, float* __restrict__ v) {
    __shared__ float gl[DH2];
    __shared__ __align__(16) float wlf[16384];   // 64 KB staging
    int bt = blockIdx.x, j = threadIdx.x;
    float ub = u2[bt * DH2 + j] + b1b[j];
    float a = 0.f;
    for (int n = 0; n < NOBJ; n++) {
        size_t idx = (size_t)(bt * NOBJ + n) * DH2 + j;
        float vv = hacc2P[idx] + hacc2P[idx + PSTR2] + ub;
        a += vv > 0.f ? vv : 0.f;
    }
    a *= (1.f / 30.f);
    gl[j] = a;
    g[bt * DH2 + j] = a;

    float aq = 0.f, ak = 0.f, av = 0.f;
    #pragma unroll 1
    for (int c = 0; c < 4; c++) {                 // Wq: 4 x (64 k-rows)
        stage64k(Wq + c * 16384, wlf, j);
        __syncthreads();
        for (int kk = 0; kk < 64; kk++)
            aq += gl[c * 64 + kk] * wlf[kk * 256 + j];
        __syncthreads();
    }
    #pragma unroll 1
    for (int c = 0; c < 4; c++) {                 // Wk
        stage64k(Wk + c * 16384, wlf, j);
        __syncthreads();
        for (int kk = 0; kk < 64; kk++)
            ak += gl[c * 64 + kk] * wlf[kk * 256 + j];
        __syncthreads();
    }
    #pragma unroll 1
    for (int c = 0; c < 4; c++) {                 // Wv
        stage64k(Wv + c * 16384, wlf, j);
        __syncthreads();
        for (int kk = 0; kk < 64; kk++)
            av += gl[c * 64 + kk] * wlf[kk * 256 + j];
        __syncthreads();
    }
    q[bt * DH2 + j] = aq;
    k[bt * DH2 + j] = ak;
    v[bt * DH2 + j] = av;
}

// -------- attn_head: 256 thr, LDS-staged weight chunks --------
__device__ __forceinline__ float block_sum256(float v, volatile float* red) {
    #pragma unroll
    for (int o = 32; o > 0; o >>= 1) v += __shfl_down(v, o);
    int w = threadIdx.x >> 6;
    __syncthreads();
    if ((threadIdx.x & 63) == 0) red[w] = v;
    __syncthreads();
    return red[0] + red[1] + red[2] + red[3];
}

__global__ __launch_bounds__(256) void attn_head(
    const float* __restrict__ qg, const float* __restrict__ kg,
    const float* __restrict__ vg, const float* __restrict__ g,
    const float* __restrict__ Wo,
    const float* __restrict__ ln1g, const float* __restrict__ ln1b,
    const float* __restrict__ Wf1, const float* __restrict__ bf1,
    const float* __restrict__ Wf2, const float* __restrict__ bf2,
    const float* __restrict__ ln2g, const float* __restrict__ ln2b,
    const float* __restrict__ Wc, const float* __restrict__ bc,
    float* __restrict__ outP) {
    __shared__ float ql[DH2];
    __shared__ float scl[4][128];
    __shared__ float ctxl[DH2];
    __shared__ float yl[DH2];
    __shared__ float ffl[DFF];
    __shared__ float red[4];
    __shared__ __align__(16) float wlf[16384];   // 64 KB staging
    int row = blockIdx.x, tid = threadIdx.x;
    int base = (row >= 100) ? 100 : 0;
    ql[tid] = qg[row * DH2 + tid];
    __syncthreads();

    for (int p = tid; p < 512; p += 256) {
        int h = p >> 7, s = p & 127;
        if (s < 100) {
            const float* kr = kg + (size_t)(base + s) * DH2 + h * 64;
            float a = 0.f;
            #pragma unroll 8
            for (int d = 0; d < 64; d++) a += ql[h * 64 + d] * kr[d];
            scl[h][s] = a * 0.125f;
        }
    }
    __syncthreads();

    {
        int w = tid >> 6, lane = tid & 63;
        int s2 = 64 + lane;
        float a  = scl[w][lane];
        float b2 = (s2 < 100) ? scl[w][s2] : -1e30f;
        float m = fmaxf(a, b2);
        #pragma unroll
        for (int o = 32; o > 0; o >>= 1) m = fmaxf(m, __shfl_down(m, o));
        m = __shfl(m, 0);
        float e1 = __expf(a - m);
        float e2 = (s2 < 100) ? __expf(b2 - m) : 0.f;
        float sm = e1 + e2;
        #pragma unroll
        for (int o = 32; o > 0; o >>= 1) sm += __shfl_down(sm, o);
        sm = __shfl(sm, 0);
        float r = 1.f / sm;
        scl[w][lane] = e1 * r;
        if (s2 < 100) scl[w][s2] = e2 * r;
    }
    __syncthreads();

    {
        int h = tid >> 6;
        float o = 0.f;
        for (int s = 0; s < 100; s++)
            o += scl[h][s] * vg[(size_t)(base + s) * DH2 + tid];
        ctxl[tid] = o;
    }
    __syncthreads();

    // Wo: 4 staged chunks of 64 k-rows (64KB each)
    float o = 0.f;
    #pragma unroll 1
    for (int c = 0; c < 4; c++) {
        stage64k(Wo + c * 16384, wlf, tid);
        __syncthreads();
        for (int kk = 0; kk < 64; kk++)
            o += ctxl[c * 64 + kk] * wlf[kk * 256 + tid];
        __syncthreads();
    }
    float t = g[row * DH2 + tid] + o;
    float mu  = block_sum256(t, red) * (1.f / DH2);
    float ex2 = block_sum256(t * t, red) * (1.f / DH2);
    float y = (t - mu) * rsqrtf(ex2 - mu * mu + 1e-5f) * ln1g[tid] + ln1b[tid];
    yl[tid] = y;
    __syncthreads();

    // FFN1: 8 staged chunks of 32 k-rows x 512 cols; 2 outputs/thread
    float a0 = 0.f, a1 = 0.f;
    #pragma unroll 1
    for (int c = 0; c < 8; c++) {
        stage64k(Wf1 + c * 16384, wlf, tid);
        __syncthreads();
        for (int kk = 0; kk < 32; kk++) {
            float x = yl[c * 32 + kk];
            a0 += x * wlf[kk * 512 + tid];
            a1 += x * wlf[kk * 512 + tid + 256];
        }
        __syncthreads();
    }
    {
        float f0 = a0 + bf1[tid];
        float f1 = a1 + bf1[tid + 256];
        ffl[tid]       = f0 > 0.f ? f0 : 0.f;
        ffl[tid + 256] = f1 > 0.f ? f1 : 0.f;
    }
    __syncthreads();

    // FFN2: 8 staged chunks of 64 k-rows x 256 cols
    float o2 = 0.f;
    #pragma unroll 1
    for (int c = 0; c < 8; c++) {
        stage64k(Wf2 + c * 16384, wlf, tid);
        __syncthreads();
        for (int kk = 0; kk < 64; kk++)
            o2 += ffl[c * 64 + kk] * wlf[kk * 256 + tid];
        __syncthreads();
    }
    float z0 = y + bf2[tid] + o2;
    float mu2  = block_sum256(z0, red) * (1.f / DH2);
    float ex22 = block_sum256(z0 * z0, red) * (1.f / DH2);
    float z = (z0 - mu2) * rsqrtf(ex22 - mu2 * mu2 + 1e-5f) * ln2g[tid] + ln2b[tid];
    float logit = block_sum256(z * Wc[tid], red) + bc[0];
    if (tid == 0) {
        outP[row]      = 1.f / (1.f + __expf(-logit));
        outP[BT + row] = 0.f;
    }
}

// ---------------- launch ----------------
extern "C" void kernel_launch(void* const* d_in, const int* in_sizes, int n_in,
                              void* d_out, int out_size, void* d_ws, size_t ws_size,
                              hipStream_t stream) {
    const float* feat  = (const float*)d_in[0];
    const float* depth = (const float*)d_in[1];
    const float* W1a = (const float*)d_in[2];
    const float* W2a = (const float*)d_in[3];
    const float* b1a = (const float*)d_in[4];
    const float* W1b = (const float*)d_in[5];
    const float* W2b = (const float*)d_in[6];
    const float* b1b = (const float*)d_in[7];
    const float* Wq  = (const float*)d_in[8];
    const float* Wk  = (const float*)d_in[9];
    const float* Wv  = (const float*)d_in[10];
    const float* Wo  = (const float*)d_in[11];
    const float* ln1g = (const float*)d_in[12];
    const float* ln1b = (const float*)d_in[13];
    const float* Wf1 = (const float*)d_in[14];
    const float* bf1 = (const float*)d_in[15];
    const float* Wf2 = (const float*)d_in[16];
    const float* bf2 = (const float*)d_in[17];
    const float* ln2g = (const float*)d_in[18];
    const float* ln2b = (const float*)d_in[19];
    const float* Wc  = (const float*)d_in[20];
    const float* bc  = (const float*)d_in[21];
    float* out = (float*)d_out;
    char* ws = (char*)d_ws;

    size_t off = 0;
    u16* XbT   = (u16*)(ws + off); off += (size_t)MPAD * KP2 * 2;    // 50.8 MB
    u16* SbT   = (u16*)(ws + off); off += (size_t)256 * KP2 * 2;     //  2.2 MB
    u16* Wc1T  = (u16*)(ws + off); off += (size_t)DH1 * KP2 * 2;     //  4.3 MB
    u16* W2aTs = (u16*)(ws + off); off += (size_t)DH1 * KP2 * 2;
    u16* Wc2T  = (u16*)(ws + off); off += (size_t)DH2 * DH1 * 2;
    u16* W2bTs = (u16*)(ws + off); off += (size_t)DH2 * DH1 * 2;
    u16* Shb   = (u16*)(ws + off); off += (size_t)256 * DH1 * 2;
    // small zero region (u/u2 only; hacc/hacc2 partials are store-once)
    char* zBase = ws + off;
    float* u     = (float*)(ws + off); off += (size_t)BT * DH1 * 4;
    float* u2    = (float*)(ws + off); off += (size_t)BT * DH2 * 4;
    size_t zeroQuads = (size_t)(ws + off - zBase) / 16;
    // split-K partial buffers: gemmA writes 3 x 12.3 MB plain-store partials;
    // after reduce1 consumes them, gemmB reuses the SAME region for its
    // 2 x 6.1 MB partials (haccP dead by then).
    float* haccP  = (float*)(ws + off); off += 3 * PSTR1 * 4;        // 36.9 MB
    float* hacc2P = haccP;
    // aliases: hb reuses XbT (dead after gemmA); g/q/k/v reuse SbT
    u16* hb = XbT;
    float* g = (float*)SbT;
    float* q = g + BT * DH2;
    float* k = q + BT * DH2;
    float* v = k + BT * DH2;

    prep_all<<<NCONV + NPAD + NZERO + NSMALL + NBIGW, 256, 0, stream>>>(
        W1a, W2a, W1b, W2b, feat, depth,
        Wc1T, W2aTs, Wc2T, W2bTs, XbT, SbT, (float*)zBase, zeroQuads);
    // haccP[z] = XbT@Wc1T (564 blocks, z=3, plain store) ; u += SbT@W2aTs (24)
    gemmA<<<564 + 24, 256, 0, stream>>>(XbT, Wc1T, SbT, W2aTs, haccP, u);
    reduce1<<<dim3(BT, 4), 256, 0, stream>>>(haccP, u, b1a, hb, Shb);
    // hacc2P[z] = hb@Wc2T (376 blocks, z=2, plain store) ; u2 += Shb@W2bTs (16)
    gemmB<<<376 + 16, 256, 0, stream>>>(hb, Wc2T, Shb, W2bTs, hacc2P, u2);
    reduce2_qkv<<<BT, 256, 0, stream>>>(hacc2P, u2, b1b, Wq, Wk, Wv, g, q, k, v);
    attn_head<<<BT, 256, 0, stream>>>(q, k, v, g, Wo, ln1g, ln1b, Wf1, bf1,
                                      Wf2, bf2, ln2g, ln2b, Wc, bc, out);
}